// Round 7
// baseline (549.583 us; speedup 1.0000x reference)
//
#include <hip/hip_runtime.h>

typedef __attribute__((ext_vector_type(4))) float f32x4;
typedef __attribute__((ext_vector_type(8))) short s16x8;
typedef __attribute__((ext_vector_type(4))) unsigned short u16x4;
typedef unsigned short ushortT;

__device__ inline ushortT f2bf(float f) {
  union { float f; unsigned u; } v; v.f = f;
  unsigned r = v.u + 0x7fffu + ((v.u >> 16) & 1u);
  return (ushortT)(r >> 16);
}
__device__ inline float bf2f(ushortT s) {
  union { unsigned u; float f; } v; v.u = ((unsigned)s) << 16;
  return v.f;
}
__device__ inline unsigned pk_bf16(float lo, float hi) {
  unsigned r;
  asm("v_cvt_pk_bf16_f32 %0, %1, %2" : "=v"(r) : "v"(lo), "v"(hi));
  return r;
}
__device__ inline ushortT cvt1_bf16(float f) {
  unsigned r;
  asm("v_cvt_pk_bf16_f32 %0, %1, %2" : "=v"(r) : "v"(f), "v"(f));
  return (ushortT)r;
}
__device__ inline f32x4 mfma16(s16x8 a, s16x8 b, f32x4 c) {
  return __builtin_amdgcn_mfma_f32_16x16x32_bf16(a, b, c, 0, 0, 0);
}
typedef const __attribute__((address_space(1))) unsigned GU;
typedef __attribute__((address_space(3))) unsigned LU;
__device__ inline void gload_lds16(const void* g, void* l) {
  __builtin_amdgcn_global_load_lds((GU*)g, (LU*)l, 16, 0, 0);
}

// lgkm-only barrier: does NOT drain vmcnt, so register prefetch of the next
// s_prev strip stays in flight across phases.
#define BARRIER_LIGHT() do {                                  \
    __builtin_amdgcn_sched_barrier(0);                        \
    asm volatile("s_waitcnt lgkmcnt(0)" ::: "memory");        \
    __builtin_amdgcn_s_barrier();                             \
    __builtin_amdgcn_sched_barrier(0);                        \
  } while (0)

// ---------------- prep kernels ----------------
__global__ void conv_bf16(const float* __restrict__ in, ushortT* __restrict__ o) {
  size_t i = ((size_t)blockIdx.x * 256 + threadIdx.x) * 4;
  f32x4 v = *(const f32x4*)(in + i);
  u16x4 u = { f2bf(v[0]), f2bf(v[1]), f2bf(v[2]), f2bf(v[3]) };
  *(u16x4*)(o + i) = u;
}

__global__ void transp_bf16(const float* __restrict__ Wm, ushortT* __restrict__ wt) {
  __shared__ float t[32][33];
  int bx = blockIdx.x, by = blockIdx.y;
  int x = threadIdx.x, y = threadIdx.y;
#pragma unroll
  for (int i = 0; i < 32; i += 8)
    t[y + i][x] = Wm[(size_t)(by * 32 + y + i) * 1024 + bx * 32 + x];
  __syncthreads();
#pragma unroll
  for (int i = 0; i < 32; i += 8)
    wt[(size_t)(bx * 32 + y + i) * 1024 + by * 32 + x] = f2bf(t[x][y + i]);
}

// ---------------- GEMM (C = A @ Bt^T), A:[M,1024] bf16, Bt:[N,1024] bf16 ----------------
template <int MODE>
__global__ __launch_bounds__(256) void gemm_bt(const ushortT* __restrict__ A,
                                               const ushortT* __restrict__ Bt,
                                               ushortT* __restrict__ o0,
                                               ushortT* __restrict__ o1,
                                               ushortT* __restrict__ o2,
                                               float* __restrict__ of) {
  __shared__ ushortT lA[128 * 32];
  __shared__ ushortT lB[128 * 32];
  const int tid = threadIdx.x;
  const int w = tid >> 6, l = tid & 63;
  const int a = l & 15, hi = l >> 4;
  const int wr = w >> 1, wc = w & 1;
  const int row0 = blockIdx.y * 128, col0 = blockIdx.x * 128;
  f32x4 acc[4][4] = {};
  const int r1 = tid >> 2, c1 = tid & 3;
  const int r2 = (tid + 256) >> 2, c2 = (tid + 256) & 3;
  for (int k0 = 0; k0 < 1024; k0 += 32) {
    __syncthreads();
    gload_lds16(A + (size_t)(row0 + r1) * 1024 + k0 + c1 * 8, &lA[r1 * 32 + c1 * 8]);
    gload_lds16(A + (size_t)(row0 + r2) * 1024 + k0 + c2 * 8, &lA[r2 * 32 + c2 * 8]);
    gload_lds16(Bt + (size_t)(col0 + r1) * 1024 + k0 + c1 * 8, &lB[r1 * 32 + c1 * 8]);
    gload_lds16(Bt + (size_t)(col0 + r2) * 1024 + k0 + c2 * 8, &lB[r2 * 32 + c2 * 8]);
    __syncthreads();
    s16x8 af[4], bfr[4];
#pragma unroll
    for (int m = 0; m < 4; ++m)
      af[m] = *(const s16x8*)&lA[(wr * 64 + m * 16 + a) * 32 + hi * 8];
#pragma unroll
    for (int n = 0; n < 4; ++n)
      bfr[n] = *(const s16x8*)&lB[(wc * 64 + n * 16 + a) * 32 + hi * 8];
#pragma unroll
    for (int m = 0; m < 4; ++m)
#pragma unroll
      for (int n = 0; n < 4; ++n)
        acc[m][n] = mfma16(af[m], bfr[n], acc[m][n]);
  }
  const int proj = col0 >> 10;
#pragma unroll
  for (int m = 0; m < 4; ++m)
#pragma unroll
    for (int n = 0; n < 4; ++n) {
      const int gr0 = row0 + wr * 64 + m * 16 + hi * 4;
      const int gc = col0 + wc * 64 + n * 16 + a;
#pragma unroll
      for (int r = 0; r < 4; ++r) {
        const int gr = gr0 + r;
        float v = acc[m][n][r];
        if (MODE == 0) {
          const int bb = gr >> 11, t = gr & 2047;
          const int cc = gc & 1023;
          const int hh = cc >> 6, d = cc & 63;
          const size_t bh = (size_t)bb * 16 + hh;
          if (proj == 0)      o0[(bh * 2048 + t) * 64 + d] = f2bf(v * 0.125f);
          else if (proj == 1) o1[(bh * 2048 + t) * 64 + d] = f2bf(v);
          else                o2[(bh * 64 + d) * 2048 + t] = f2bf(v);
        } else {
          of[(size_t)gr * 1024 + gc] = v;
        }
      }
    }
}

// ---------------- fused attention: 4 items/block, XCD-local K/V, nt streams ----------------
#define SBS 2056
__global__ __launch_bounds__(512, 4) void attn_fused(
    const ushortT* __restrict__ qw, const ushortT* __restrict__ kw,
    const ushortT* __restrict__ vtw, const float* __restrict__ sprev,
    const float* __restrict__ alpha, const float* __restrict__ gamma,
    const float* __restrict__ beta, float* __restrict__ raw,
    ushortT* __restrict__ merged) {
  __shared__ ushortT sb[16 * SBS];
  __shared__ float c0_s[16], c1_s[16], li_s[16];
  __shared__ float red[4][64][4];
  // bijective XCD swizzle (1024 % 8 == 0): XCD x runs wg ids [x*128, x*128+128)
  // => each XCD touches only 4 bh => K+V working set 2 MB, L2-resident.
  const int bid = blockIdx.x;
  const int wg = (bid & 7) * 128 + (bid >> 3);
  const int j = wg & 31, h = (wg >> 5) & 15, b = wg >> 9;
  const int bh = b * 16 + h;
  const int tid = threadIdx.x;
  const int w = tid >> 6, l = tid & 63;
  const int a = l & 15, hi = l >> 4;

  const float gate = 1.f / (1.f + __expf(-alpha[h]));
  const float gm = gamma[h], bt = beta[h];
  const ushortT* kbp = kw + (size_t)bh * 2048 * 64;
  const float* spb = sprev + (size_t)bh * 2048 * 2048;

  f32x4 pre[2][8];
  // prologue: prefetch item 0's s_prev strip (nontemporal)
  {
    const int t0 = j * 16;
#pragma unroll
    for (int rr = 0; rr < 2; ++rr) {
      const float* rp = spb + (size_t)(t0 + 2 * w + rr) * 2048 + 4 * l;
#pragma unroll
      for (int i = 0; i < 8; ++i)
        pre[rr][i] = __builtin_nontemporal_load((const f32x4*)(rp + 256 * i));
    }
  }

  for (int it = 0; it < 4; ++it) {
    const int t0 = j * 16 + it * 512;
    BARRIER_LIGHT();  // sb free (previous item's PV reads done)

    // phase 1: stats + bf16 pack from prefetched regs (2 rows/wave)
#pragma unroll
    for (int rr = 0; rr < 2; ++rr) {
      const int row = 2 * w + rr;
      float sum = 0.f, sq = 0.f;
#pragma unroll
      for (int i = 0; i < 8; ++i) {
        f32x4 v = pre[rr][i];
        sum += v[0] + v[1] + v[2] + v[3];
        sq += v[0] * v[0] + v[1] * v[1] + v[2] * v[2] + v[3] * v[3];
        uint2 u;
        u.x = pk_bf16(v[0], v[1]);
        u.y = pk_bf16(v[2], v[3]);
        *(uint2*)&sb[row * SBS + 4 * l + 256 * i] = u;
      }
#pragma unroll
      for (int s = 32; s >= 1; s >>= 1) {
        sum += __shfl_xor(sum, s);
        sq += __shfl_xor(sq, s);
      }
      if (l == 0) {
        float mu = sum * (1.f / 2048.f);
        float var = fmaxf(sq * (1.f / 2048.f) - mu * mu, 0.f);
        float rs = 1.f / (sqrtf(var) + 1e-5f);
        c1_s[row] = gate * gm * rs;
        c0_s[row] = gate * (bt - gm * mu * rs);
      }
    }
    BARRIER_LIGHT();

    // phase 2: QK^T + gated norm add; raw (nt store); masked scores -> LDS.
    // K fragments software-pipelined 1 iteration deep.
    const ushortT* qrow = qw + ((size_t)bh * 2048 + t0 + a) * 64;
    s16x8 qf0 = *(const s16x8*)(qrow + hi * 8);
    s16x8 qf1 = *(const s16x8*)(qrow + 32 + hi * 8);
    float c04[4], c14[4];
#pragma unroll
    for (int r = 0; r < 4; ++r) {
      c04[r] = c0_s[4 * hi + r];
      c14[r] = c1_s[4 * hi + r];
    }
    float* rawb = raw + ((size_t)bh * 2048 + t0) * 2048;
    const ushortT* kr0 = kbp + (size_t)(w * 16 + a) * 64 + hi * 8;
    s16x8 ka = *(const s16x8*)(kr0);
    s16x8 kb2 = *(const s16x8*)(kr0 + 32);
    for (int i = 0; i < 16; ++i) {
      const int col0 = (w + 8 * i) * 16;
      s16x8 na, nb2;
      if (i < 15) {
        const ushortT* krn = kbp + (size_t)(col0 + 128 + a) * 64 + hi * 8;
        na = *(const s16x8*)(krn);
        nb2 = *(const s16x8*)(krn + 32);
      }
      f32x4 s4 = {};
      s4 = mfma16(qf0, ka, s4);
      s4 = mfma16(qf1, kb2, s4);
#pragma unroll
      for (int r = 0; r < 4; ++r) {
        const int rl = 4 * hi + r;
        const float spv = bf2f(sb[rl * SBS + col0 + a]);
        const float rv = fmaf(c14[r], spv, s4[r] + c04[r]);
        __builtin_nontemporal_store(rv, &rawb[(size_t)rl * 2048 + col0 + a]);
        sb[rl * SBS + col0 + a] = cvt1_bf16((col0 + a) <= (t0 + rl) ? rv : -1e30f);
      }
      ka = na; kb2 = nb2;
    }

    // prefetch next item's s_prev strip (nt; hides under softmax + PV)
    if (it < 3) {
      const int t0n = j * 16 + (it + 1) * 512;
#pragma unroll
      for (int rr = 0; rr < 2; ++rr) {
        const float* rp = spb + (size_t)(t0n + 2 * w + rr) * 2048 + 4 * l;
#pragma unroll
        for (int i = 0; i < 8; ++i)
          pre[rr][i] = __builtin_nontemporal_load((const f32x4*)(rp + 256 * i));
      }
    }
    BARRIER_LIGHT();

    // phase 3: full-row softmax, two LDS passes, 2 rows/wave
#pragma unroll
    for (int rr = 0; rr < 2; ++rr) {
      const int row = 2 * w + rr;
      float m = -3e38f;
#pragma unroll
      for (int i = 0; i < 16; ++i) {
        unsigned u = *(const unsigned*)&sb[row * SBS + 2 * l + 128 * i];
        union { unsigned u; float f; } lo, hh;
        lo.u = u << 16; hh.u = u & 0xffff0000u;
        m = fmaxf(m, fmaxf(lo.f, hh.f));
      }
#pragma unroll
      for (int s = 32; s >= 1; s >>= 1) m = fmaxf(m, __shfl_xor(m, s));
      float sum = 0.f;
#pragma unroll
      for (int i = 0; i < 16; ++i) {
        unsigned u = *(const unsigned*)&sb[row * SBS + 2 * l + 128 * i];
        union { unsigned u; float f; } lo, hh;
        lo.u = u << 16; hh.u = u & 0xffff0000u;
        float e0 = __expf(lo.f - m);
        float e1 = __expf(hh.f - m);
        sum += e0 + e1;
        *(unsigned*)&sb[row * SBS + 2 * l + 128 * i] = pk_bf16(e0, e1);
      }
#pragma unroll
      for (int s = 32; s >= 1; s >>= 1) sum += __shfl_xor(sum, s);
      if (l == 0) li_s[row] = 1.f / sum;
    }
    BARRIER_LIGHT();

    // phase 4: PV. 4 col-tiles (n), K-range split across wave pairs (half).
    // V fragments pipelined 4 deep (static indices only).
    const int n = w & 3, half = w >> 2;
    const ushortT* vb = vtw + ((size_t)bh * 64 + 16 * n + a) * 2048;
    f32x4 acc = {};
    const int nch = (t0 + 47) >> 5;
    {
      s16x8 v0, v1, v2, v3;
      const int c0i = half;
      if (c0i + 0 < nch) v0 = *(const s16x8*)(vb + 32 * (c0i + 0) + 8 * hi);
      if (c0i + 2 < nch) v1 = *(const s16x8*)(vb + 32 * (c0i + 2) + 8 * hi);
      if (c0i + 4 < nch) v2 = *(const s16x8*)(vb + 32 * (c0i + 4) + 8 * hi);
      if (c0i + 6 < nch) v3 = *(const s16x8*)(vb + 32 * (c0i + 6) + 8 * hi);
      for (int cc = c0i; cc < nch; cc += 8) {
        if (cc + 0 < nch) {
          s16x8 pf = *(const s16x8*)&sb[a * SBS + 32 * (cc + 0) + 8 * hi];
          acc = mfma16(pf, v0, acc);
          if (cc + 8 < nch) v0 = *(const s16x8*)(vb + 32 * (cc + 8) + 8 * hi);
        }
        if (cc + 2 < nch) {
          s16x8 pf = *(const s16x8*)&sb[a * SBS + 32 * (cc + 2) + 8 * hi];
          acc = mfma16(pf, v1, acc);
          if (cc + 10 < nch) v1 = *(const s16x8*)(vb + 32 * (cc + 10) + 8 * hi);
        }
        if (cc + 4 < nch) {
          s16x8 pf = *(const s16x8*)&sb[a * SBS + 32 * (cc + 4) + 8 * hi];
          acc = mfma16(pf, v2, acc);
          if (cc + 12 < nch) v2 = *(const s16x8*)(vb + 32 * (cc + 12) + 8 * hi);
        }
        if (cc + 6 < nch) {
          s16x8 pf = *(const s16x8*)&sb[a * SBS + 32 * (cc + 6) + 8 * hi];
          acc = mfma16(pf, v3, acc);
          if (cc + 14 < nch) v3 = *(const s16x8*)(vb + 32 * (cc + 14) + 8 * hi);
        }
      }
    }
    if (half == 1) *(f32x4*)red[n][l] = acc;
    BARRIER_LIGHT();
    if (half == 0) {
      f32x4 o = *(f32x4*)red[n][l];
      acc += o;
#pragma unroll
      for (int r = 0; r < 4; ++r) {
        const int rl = 4 * hi + r;
        const float cx = acc[r] * li_s[rl];
        merged[((size_t)b * 2048 + t0 + rl) * 1024 + h * 64 + 16 * n + a] = f2bf(cx);
      }
    }
  }
}

extern "C" void kernel_launch(void* const* d_in, const int* in_sizes, int n_in,
                              void* d_out, int out_size, void* d_ws, size_t ws_size,
                              hipStream_t stream) {
  (void)in_sizes; (void)n_in; (void)out_size; (void)ws_size;
  const float* x      = (const float*)d_in[0];
  const float* s_prev = (const float*)d_in[1];
  const float* Wq     = (const float*)d_in[2];
  const float* Wk     = (const float*)d_in[3];
  const float* Wv     = (const float*)d_in[4];
  const float* Wo     = (const float*)d_in[5];
  const float* alpha  = (const float*)d_in[6];
  const float* gamma  = (const float*)d_in[7];
  const float* beta   = (const float*)d_in[8];

  float* out = (float*)d_out;
  float* raw = out + (size_t)4194304;  // B*T*HID

  char* ws = (char*)d_ws;
  const size_t MB = 1024 * 1024;
  ushortT* xb  = (ushortT*)(ws);             // 8 MB
  ushortT* wT  = (ushortT*)(ws + 8 * MB);    // 6 MB  (Wq|Wk|Wv col-major bf16)
  ushortT* woT = (ushortT*)(ws + 14 * MB);   // 2 MB
  ushortT* qw  = (ushortT*)(ws + 16 * MB);   // 8 MB  (B,H,T,D)
  ushortT* kw  = (ushortT*)(ws + 24 * MB);   // 8 MB  (B,H,T,D)
  ushortT* vtw = (ushortT*)(ws + 32 * MB);   // 8 MB  (B,H,D,T)
  ushortT* mg  = (ushortT*)(ws + 40 * MB);   // 8 MB  (B,T,H*D)

  conv_bf16<<<4096, 256, 0, stream>>>(x, xb);
  dim3 tb(32, 8);
  transp_bf16<<<dim3(32, 32), tb, 0, stream>>>(Wq, wT);
  transp_bf16<<<dim3(32, 32), tb, 0, stream>>>(Wk, wT + 1024 * 1024);
  transp_bf16<<<dim3(32, 32), tb, 0, stream>>>(Wv, wT + 2 * 1024 * 1024);
  transp_bf16<<<dim3(32, 32), tb, 0, stream>>>(Wo, woT);

  gemm_bt<0><<<dim3(24, 32), 256, 0, stream>>>(xb, wT, qw, kw, vtw, nullptr);

  attn_fused<<<1024, 512, 0, stream>>>(qw, kw, vtw, s_prev, alpha, gamma,
                                       beta, raw, mg);

  gemm_bt<1><<<dim3(8, 32), 256, 0, stream>>>(mg, woT, nullptr, nullptr, nullptr, out);
}

// Round 8
// 444.759 us; speedup vs baseline: 1.2357x; 1.2357x over previous
//
#include <hip/hip_runtime.h>

typedef __attribute__((ext_vector_type(4))) float f32x4;
typedef __attribute__((ext_vector_type(8))) short s16x8;
typedef __attribute__((ext_vector_type(4))) unsigned short u16x4;
typedef unsigned short ushortT;

__device__ inline ushortT f2bf(float f) {
  union { float f; unsigned u; } v; v.f = f;
  unsigned r = v.u + 0x7fffu + ((v.u >> 16) & 1u);
  return (ushortT)(r >> 16);
}
__device__ inline float bf2f(ushortT s) {
  union { unsigned u; float f; } v; v.u = ((unsigned)s) << 16;
  return v.f;
}
__device__ inline unsigned pk_bf16(float lo, float hi) {
  unsigned r;
  asm("v_cvt_pk_bf16_f32 %0, %1, %2" : "=v"(r) : "v"(lo), "v"(hi));
  return r;
}
__device__ inline ushortT cvt1_bf16(float f) {
  unsigned r;
  asm("v_cvt_pk_bf16_f32 %0, %1, %2" : "=v"(r) : "v"(f), "v"(f));
  return (ushortT)r;
}
__device__ inline f32x4 mfma16(s16x8 a, s16x8 b, f32x4 c) {
  return __builtin_amdgcn_mfma_f32_16x16x32_bf16(a, b, c, 0, 0, 0);
}
typedef const __attribute__((address_space(1))) unsigned GU;
typedef __attribute__((address_space(3))) unsigned LU;
__device__ inline void gload_lds16(const void* g, void* l) {
  __builtin_amdgcn_global_load_lds((GU*)g, (LU*)l, 16, 0, 0);
}

// lgkm-only barrier: does NOT drain vmcnt, so producer-wave streaming loads
// stay in flight across phase boundaries.
#define BARRIER_LIGHT() do {                                  \
    __builtin_amdgcn_sched_barrier(0);                        \
    asm volatile("s_waitcnt lgkmcnt(0)" ::: "memory");        \
    __builtin_amdgcn_s_barrier();                             \
    __builtin_amdgcn_sched_barrier(0);                        \
  } while (0)

// ---------------- prep kernels ----------------
__global__ void conv_bf16(const float* __restrict__ in, ushortT* __restrict__ o) {
  size_t i = ((size_t)blockIdx.x * 256 + threadIdx.x) * 4;
  f32x4 v = *(const f32x4*)(in + i);
  u16x4 u = { f2bf(v[0]), f2bf(v[1]), f2bf(v[2]), f2bf(v[3]) };
  *(u16x4*)(o + i) = u;
}

__global__ void transp_bf16(const float* __restrict__ Wm, ushortT* __restrict__ wt) {
  __shared__ float t[32][33];
  int bx = blockIdx.x, by = blockIdx.y;
  int x = threadIdx.x, y = threadIdx.y;
#pragma unroll
  for (int i = 0; i < 32; i += 8)
    t[y + i][x] = Wm[(size_t)(by * 32 + y + i) * 1024 + bx * 32 + x];
  __syncthreads();
#pragma unroll
  for (int i = 0; i < 32; i += 8)
    wt[(size_t)(bx * 32 + y + i) * 1024 + by * 32 + x] = f2bf(t[x][y + i]);
}

// ---------------- GEMM (C = A @ Bt^T), A:[M,1024] bf16, Bt:[N,1024] bf16 ----------------
template <int MODE>
__global__ __launch_bounds__(256) void gemm_bt(const ushortT* __restrict__ A,
                                               const ushortT* __restrict__ Bt,
                                               ushortT* __restrict__ o0,
                                               ushortT* __restrict__ o1,
                                               ushortT* __restrict__ o2,
                                               float* __restrict__ of) {
  __shared__ ushortT lA[128 * 32];
  __shared__ ushortT lB[128 * 32];
  const int tid = threadIdx.x;
  const int w = tid >> 6, l = tid & 63;
  const int a = l & 15, hi = l >> 4;
  const int wr = w >> 1, wc = w & 1;
  const int row0 = blockIdx.y * 128, col0 = blockIdx.x * 128;
  f32x4 acc[4][4] = {};
  const int r1 = tid >> 2, c1 = tid & 3;
  const int r2 = (tid + 256) >> 2, c2 = (tid + 256) & 3;
  for (int k0 = 0; k0 < 1024; k0 += 32) {
    __syncthreads();
    gload_lds16(A + (size_t)(row0 + r1) * 1024 + k0 + c1 * 8, &lA[r1 * 32 + c1 * 8]);
    gload_lds16(A + (size_t)(row0 + r2) * 1024 + k0 + c2 * 8, &lA[r2 * 32 + c2 * 8]);
    gload_lds16(Bt + (size_t)(col0 + r1) * 1024 + k0 + c1 * 8, &lB[r1 * 32 + c1 * 8]);
    gload_lds16(Bt + (size_t)(col0 + r2) * 1024 + k0 + c2 * 8, &lB[r2 * 32 + c2 * 8]);
    __syncthreads();
    s16x8 af[4], bfr[4];
#pragma unroll
    for (int m = 0; m < 4; ++m)
      af[m] = *(const s16x8*)&lA[(wr * 64 + m * 16 + a) * 32 + hi * 8];
#pragma unroll
    for (int n = 0; n < 4; ++n)
      bfr[n] = *(const s16x8*)&lB[(wc * 64 + n * 16 + a) * 32 + hi * 8];
#pragma unroll
    for (int m = 0; m < 4; ++m)
#pragma unroll
      for (int n = 0; n < 4; ++n)
        acc[m][n] = mfma16(af[m], bfr[n], acc[m][n]);
  }
  const int proj = col0 >> 10;
#pragma unroll
  for (int m = 0; m < 4; ++m)
#pragma unroll
    for (int n = 0; n < 4; ++n) {
      const int gr0 = row0 + wr * 64 + m * 16 + hi * 4;
      const int gc = col0 + wc * 64 + n * 16 + a;
#pragma unroll
      for (int r = 0; r < 4; ++r) {
        const int gr = gr0 + r;
        float v = acc[m][n][r];
        if (MODE == 0) {
          const int bb = gr >> 11, t = gr & 2047;
          const int cc = gc & 1023;
          const int hh = cc >> 6, d = cc & 63;
          const size_t bh = (size_t)bb * 16 + hh;
          if (proj == 0)      o0[(bh * 2048 + t) * 64 + d] = f2bf(v * 0.125f);
          else if (proj == 1) o1[(bh * 2048 + t) * 64 + d] = f2bf(v);
          else                o2[(bh * 64 + d) * 2048 + t] = f2bf(v);
        } else {
          of[(size_t)gr * 1024 + gc] = v;
        }
      }
    }
}

// ---------------- fused attention: wave-specialized producer/consumer ----------------
// 1 block/CU, 1024 threads (16 waves): waves 0-3 stream s_prev (next item) into
// the spare LDS buffer + stats; waves 4-15 do QK^T + raw + softmax + PV on the
// current buffer. Producer vmcnt queues contain ONLY the HBM stream, so it
// drains continuously across all phases (in-order vmcnt can't block compute).
#define SBS 2056
__global__ __launch_bounds__(1024, 4) void attn_fused(
    const ushortT* __restrict__ qw, const ushortT* __restrict__ kw,
    const ushortT* __restrict__ vtw, const float* __restrict__ sprev,
    const float* __restrict__ alpha, const float* __restrict__ gamma,
    const float* __restrict__ beta, float* __restrict__ raw,
    ushortT* __restrict__ merged) {
  __shared__ ushortT sb[2][16 * SBS];
  __shared__ float c0_s[2][16], c1_s[2][16], li_s[16];
  __shared__ float red[2][4][64][4];

  // 256 blocks; XCD x (bid&7) hosts bh = x*4 + (idx&3)  -> 4 bh per XCD,
  // K+V working set 2 MB (L2-resident). jslot = per-bh strip slot (8 blocks/bh).
  const int bid = blockIdx.x;
  const int xcd = bid & 7, idx = bid >> 3;
  const int bh = xcd * 4 + (idx & 3);
  const int jslot = idx >> 2;
  const int h = bh & 15, b = bh >> 4;
  const int tid = threadIdx.x;
  const int w = tid >> 6, l = tid & 63;
  const int a = l & 15, hi = l >> 4;

  const float gate = 1.f / (1.f + __expf(-alpha[h]));
  const float gm = gamma[h], bt = beta[h];
  const ushortT* kbp = kw + (size_t)bh * 2048 * 64;
  const float* spb = sprev + (size_t)bh * 2048 * 2048;

  // producer: one s_prev row -> bf16 pack into sb[nb] + c0/c1 stats
  auto prod_row = [&](int t0n, int row, int nb) {
    const float* rp = spb + (size_t)(t0n + row) * 2048 + 4 * l;
    ushortT* dst = &sb[nb][row * SBS + 4 * l];
    float sum = 0.f, sq = 0.f;
#pragma unroll
    for (int i = 0; i < 8; ++i) {
      f32x4 v = __builtin_nontemporal_load((const f32x4*)(rp + 256 * i));
      sum += v[0] + v[1] + v[2] + v[3];
      sq += v[0] * v[0] + v[1] * v[1] + v[2] * v[2] + v[3] * v[3];
      uint2 u;
      u.x = pk_bf16(v[0], v[1]);
      u.y = pk_bf16(v[2], v[3]);
      *(uint2*)&dst[256 * i] = u;
    }
#pragma unroll
    for (int s = 32; s >= 1; s >>= 1) {
      sum += __shfl_xor(sum, s);
      sq += __shfl_xor(sq, s);
    }
    if (l == 0) {
      float mu = sum * (1.f / 2048.f);
      float var = fmaxf(sq * (1.f / 2048.f) - mu * mu, 0.f);
      float rs = 1.f / (sqrtf(var) + 1e-5f);
      c1_s[nb][row] = gate * gm * rs;
      c0_s[nb][row] = gate * (bt - gm * mu * rs);
    }
  };

  // prologue: fill buffer 0 with item 0
  if (w < 4) {
    const int t00 = jslot * 16;
    prod_row(t00, w, 0);
    prod_row(t00, w + 4, 0);
    prod_row(t00, w + 8, 0);
    prod_row(t00, w + 12, 0);
  }
  BARRIER_LIGHT();

  for (int it = 0; it < 16; ++it) {
    const int t0 = jslot * 16 + it * 128;       // interleaved strips: balanced triangle
    const int cb = it & 1, nb = cb ^ 1;
    const int t0n = jslot * 16 + (it + 1) * 128;
    const bool dopre = (it < 15);
    ushortT* sbc = sb[cb];

    if (w < 4) {
      // -------- producers: stream item it+1, paced across the 3 intervals ----
      if (dopre) { prod_row(t0n, w, nb); prod_row(t0n, w + 4, nb); }
      BARRIER_LIGHT();  // matches consumers' post-ph2 barrier
      if (dopre) prod_row(t0n, w + 8, nb);
      BARRIER_LIGHT();  // post-ph3
      if (dopre) prod_row(t0n, w + 12, nb);
      BARRIER_LIGHT();  // post-ph4 (red ready)
      BARRIER_LIGHT();  // item boundary
    } else {
      const int cw = w - 4;  // 0..11
      // -------- ph2: QK^T + gated norm; raw store; masked scores -> sbc ------
      {
        const ushortT* qrow = qw + ((size_t)bh * 2048 + t0 + a) * 64;
        s16x8 qf0 = *(const s16x8*)(qrow + hi * 8);
        s16x8 qf1 = *(const s16x8*)(qrow + 32 + hi * 8);
        float c04[4], c14[4];
#pragma unroll
        for (int r = 0; r < 4; ++r) {
          c04[r] = c0_s[cb][4 * hi + r];
          c14[r] = c1_s[cb][4 * hi + r];
        }
        float* rawb = raw + ((size_t)bh * 2048 + t0) * 2048;
        for (int tIdx = cw; tIdx < 128; tIdx += 12) {
          const int col0 = tIdx * 16;
          const ushortT* kr = kbp + (size_t)(col0 + a) * 64 + hi * 8;
          s16x8 kf0 = *(const s16x8*)(kr);
          s16x8 kf1 = *(const s16x8*)(kr + 32);
          f32x4 s4 = {};
          s4 = mfma16(qf0, kf0, s4);
          s4 = mfma16(qf1, kf1, s4);
#pragma unroll
          for (int r = 0; r < 4; ++r) {
            const int rl = 4 * hi + r;
            const float spv = bf2f(sbc[rl * SBS + col0 + a]);
            const float rv = fmaf(c14[r], spv, s4[r] + c04[r]);
            rawb[(size_t)rl * 2048 + col0 + a] = rv;
            sbc[rl * SBS + col0 + a] = cvt1_bf16((col0 + a) <= (t0 + rl) ? rv : -1e30f);
          }
        }
      }
      BARRIER_LIGHT();
      // -------- ph3: full-row softmax (rows cw, cw+12) -----------------------
      for (int row = cw; row < 16; row += 12) {
        float m = -3e38f;
#pragma unroll
        for (int i = 0; i < 16; ++i) {
          unsigned u = *(const unsigned*)&sbc[row * SBS + 2 * l + 128 * i];
          union { unsigned u; float f; } lo, hh;
          lo.u = u << 16; hh.u = u & 0xffff0000u;
          m = fmaxf(m, fmaxf(lo.f, hh.f));
        }
#pragma unroll
        for (int s = 32; s >= 1; s >>= 1) m = fmaxf(m, __shfl_xor(m, s));
        float sum = 0.f;
#pragma unroll
        for (int i = 0; i < 16; ++i) {
          unsigned u = *(const unsigned*)&sbc[row * SBS + 2 * l + 128 * i];
          union { unsigned u; float f; } lo, hh;
          lo.u = u << 16; hh.u = u & 0xffff0000u;
          float e0 = __expf(lo.f - m);
          float e1 = __expf(hh.f - m);
          sum += e0 + e1;
          *(unsigned*)&sbc[row * SBS + 2 * l + 128 * i] = pk_bf16(e0, e1);
        }
#pragma unroll
        for (int s = 32; s >= 1; s >>= 1) sum += __shfl_xor(sum, s);
        if (l == 0) li_s[row] = 1.f / sum;
      }
      BARRIER_LIGHT();
      // -------- ph4: PV, 4 col-tiles x 3-way K split -------------------------
      const int n = cw & 3, third = cw >> 2;
      const ushortT* vb = vtw + ((size_t)bh * 64 + 16 * n + a) * 2048;
      f32x4 acc = {};
      const int nch = (t0 + 47) >> 5;
      for (int c = third; c < nch; c += 3) {
        s16x8 pf = *(const s16x8*)&sbc[a * SBS + 32 * c + 8 * hi];
        s16x8 vf = *(const s16x8*)(vb + 32 * c + 8 * hi);
        acc = mfma16(pf, vf, acc);
      }
      if (third) *(f32x4*)red[third - 1][n][l] = acc;
      BARRIER_LIGHT();
      if (third == 0) {
        f32x4 p1 = *(f32x4*)red[0][n][l];
        f32x4 p2 = *(f32x4*)red[1][n][l];
        acc += p1 + p2;
#pragma unroll
        for (int r = 0; r < 4; ++r) {
          const int rl = 4 * hi + r;
          merged[((size_t)b * 2048 + t0 + rl) * 1024 + h * 64 + 16 * n + a] =
              f2bf(acc[r] * li_s[rl]);
        }
      }
      BARRIER_LIGHT();  // item boundary
    }
  }
}

extern "C" void kernel_launch(void* const* d_in, const int* in_sizes, int n_in,
                              void* d_out, int out_size, void* d_ws, size_t ws_size,
                              hipStream_t stream) {
  (void)in_sizes; (void)n_in; (void)out_size; (void)ws_size;
  const float* x      = (const float*)d_in[0];
  const float* s_prev = (const float*)d_in[1];
  const float* Wq     = (const float*)d_in[2];
  const float* Wk     = (const float*)d_in[3];
  const float* Wv     = (const float*)d_in[4];
  const float* Wo     = (const float*)d_in[5];
  const float* alpha  = (const float*)d_in[6];
  const float* gamma  = (const float*)d_in[7];
  const float* beta   = (const float*)d_in[8];

  float* out = (float*)d_out;
  float* raw = out + (size_t)4194304;  // B*T*HID

  char* ws = (char*)d_ws;
  const size_t MB = 1024 * 1024;
  ushortT* xb  = (ushortT*)(ws);             // 8 MB
  ushortT* wT  = (ushortT*)(ws + 8 * MB);    // 6 MB  (Wq|Wk|Wv col-major bf16)
  ushortT* woT = (ushortT*)(ws + 14 * MB);   // 2 MB
  ushortT* qw  = (ushortT*)(ws + 16 * MB);   // 8 MB  (B,H,T,D)
  ushortT* kw  = (ushortT*)(ws + 24 * MB);   // 8 MB  (B,H,T,D)
  ushortT* vtw = (ushortT*)(ws + 32 * MB);   // 8 MB  (B,H,D,T)
  ushortT* mg  = (ushortT*)(ws + 40 * MB);   // 8 MB  (B,T,H*D)

  conv_bf16<<<4096, 256, 0, stream>>>(x, xb);
  dim3 tb(32, 8);
  transp_bf16<<<dim3(32, 32), tb, 0, stream>>>(Wq, wT);
  transp_bf16<<<dim3(32, 32), tb, 0, stream>>>(Wk, wT + 1024 * 1024);
  transp_bf16<<<dim3(32, 32), tb, 0, stream>>>(Wv, wT + 2 * 1024 * 1024);
  transp_bf16<<<dim3(32, 32), tb, 0, stream>>>(Wo, woT);

  gemm_bt<0><<<dim3(24, 32), 256, 0, stream>>>(xb, wT, qw, kw, vtw, nullptr);

  attn_fused<<<256, 1024, 0, stream>>>(qw, kw, vtw, s_prev, alpha, gamma,
                                       beta, raw, mg);

  gemm_bt<1><<<dim3(8, 32), 256, 0, stream>>>(mg, woT, nullptr, nullptr, nullptr, out);
}